// Round 1
// baseline (799.928 us; speedup 1.0000x reference)
//
#include <hip/hip_runtime.h>
#include <math.h>

#define NX 256
#define NY 256
#define N_STEPS 300
#define N_CELLS (NX * NY)

// f32 constants, folded from the double-precision python constants exactly as
// XLA would fold them at trace time (double arithmetic -> cast to f32 at use).
__device__ __constant__ float kINV_DX      = 1280.0f;              // 1/(0.2/256)
__device__ __constant__ float kINV_DY      = 1280.0f;
__device__ __constant__ float kDT          = 2.5e-5f;
__device__ __constant__ float kMU          = 25000.0f;             // 1000*5*5
__device__ __constant__ float kETA         = 0.1f;
__device__ __constant__ float kDT_OVER_RHO = 2.5e-8f;
__device__ __constant__ float kONE_MINUS_BD = 0.99999975f;         // 1 - 0.01*2.5e-5
__device__ __constant__ float kNEG_INV_2SIG2 = -55555.5546875f;    // -1/(2*0.003^2) as f32
__device__ __constant__ float kDX          = 7.8125e-4f;           // 0.2/256
__device__ __constant__ float kEPS         = 1e-8f;

// PML damping profile value for 1-D index k (0..255)
__device__ __forceinline__ float dprof(int k) {
    int m = (k < NX - 1 - k) ? k : (NX - 1 - k);   // mirror: right edge is factor[::-1]
    if (m >= 20) return 1.0f;
    // factor[m] = 1 - 0.05*(0.5 + 0.5*cos(pi*(20-m)/20))
    float arg = (float)(M_PI) * (float)(20 - m) / 20.0f;
    return 1.0f - 0.05f * (0.5f + 0.5f * cosf(arg));
}

__global__ __launch_bounds__(256) void init_kernel(float* __restrict__ vz,
                                                   float* __restrict__ sxz,
                                                   float* __restrict__ syz,
                                                   float* __restrict__ damping) {
    int idx = blockIdx.x * 256 + threadIdx.x;
    int i = idx >> 8;      // x index (row)
    int j = idx & 255;     // y index (col)
    vz[idx]  = 0.0f;
    sxz[idx] = 0.0f;
    syz[idx] = 0.0f;
    damping[idx] = dprof(i) * dprof(j);
}

__global__ __launch_bounds__(256) void step_kernel(
    const float* __restrict__ vz_in,
    const float* __restrict__ sxz_in,
    const float* __restrict__ syz_in,
    float* __restrict__ vz_out,
    float* __restrict__ sxz_out,
    float* __restrict__ syz_out,
    const float* __restrict__ damping,
    const float2* __restrict__ traj,
    int t,
    float* __restrict__ out_vz,
    float* __restrict__ out_stress)
{
    const int j = threadIdx.x;       // y (contiguous)
    const int i = blockIdx.x;        // x (row)
    const int idx = i * NY + j;

    // source position (uniform -> scalar load)
    const float2 xy = traj[t];
    const float x_t = xy.x;
    const float y_t = xy.y;

    // load vz stencil
    const float vz_c  = vz_in[idx];
    const float vz_xp = (i < NX - 1) ? vz_in[idx + NY] : 0.0f;
    const float vz_xm = (i > 0)      ? vz_in[idx - NY] : 0.0f;
    const float vz_yp = (j < NY - 1) ? vz_in[idx + 1]  : 0.0f;
    const float vz_ym = (j > 0)      ? vz_in[idx - 1]  : 0.0f;

    // forward differences (zero at trailing edge)
    const float dvx_c = (i < NX - 1) ? (vz_xp - vz_c) * kINV_DX : 0.0f;
    const float dvy_c = (j < NY - 1) ? (vz_yp - vz_c) * kINV_DY : 0.0f;
    // forward difference evaluated at (i-1, j) / (i, j-1); i-1 <= 254 so always interior formula
    const float dvx_m = (vz_c - vz_xm) * kINV_DX;
    const float dvy_m = (vz_c - vz_ym) * kINV_DY;

    // Kelvin-Voigt stress at own cell (with updated strain)
    const float sxz_c = sxz_in[idx] + dvx_c * kDT;
    const float syz_c = syz_in[idx] + dvy_c * kDT;
    const float sig_x_c = kMU * sxz_c + kETA * dvx_c;
    const float sig_y_c = kMU * syz_c + kETA * dvy_c;

    // backward difference of stress (zero at leading edge); recompute neighbor sigma
    float ds_dx = 0.0f;
    if (i > 0) {
        const float sxz_m   = sxz_in[idx - NY] + dvx_m * kDT;
        const float sig_x_m = kMU * sxz_m + kETA * dvx_m;
        ds_dx = (sig_x_c - sig_x_m) * kINV_DX;
    }
    float ds_dy = 0.0f;
    if (j > 0) {
        const float syz_m   = syz_in[idx - 1] + dvy_m * kDT;
        const float sig_y_m = kMU * syz_m + kETA * dvy_m;
        ds_dy = (sig_y_c - sig_y_m) * kINV_DY;
    }

    // Gaussian source
    const float xi = ((float)i + 0.5f) * kDX;
    const float yj = ((float)j + 0.5f) * kDX;
    const float rx = xi - x_t;
    const float ry = yj - y_t;
    const float r_sq = rx * rx + ry * ry;
    const float source = expf(r_sq * kNEG_INV_2SIG2);

    // velocity update + bulk damping + PML
    float vz_new = vz_c + kDT_OVER_RHO * (ds_dx + ds_dy + source);
    vz_new *= kONE_MINUS_BD;
    vz_new *= damping[idx];

    vz_out[idx]  = vz_new;
    sxz_out[idx] = sxz_c;
    syz_out[idx] = syz_c;

    out_vz[idx]     = vz_new;
    out_stress[idx] = sqrtf(sig_x_c * sig_x_c + sig_y_c * sig_y_c + kEPS);
}

extern "C" void kernel_launch(void* const* d_in, const int* in_sizes, int n_in,
                              void* d_out, int out_size, void* d_ws, size_t ws_size,
                              hipStream_t stream) {
    const float2* traj = (const float2*)d_in[0];
    float* out = (float*)d_out;
    float* ws  = (float*)d_ws;

    // workspace layout: vz[2], sxz[2], syz[2], damping  -> 7 * 64K floats = 1.75 MB
    float* vz[2]  = { ws + 0 * N_CELLS, ws + 1 * N_CELLS };
    float* sxz[2] = { ws + 2 * N_CELLS, ws + 3 * N_CELLS };
    float* syz[2] = { ws + 4 * N_CELLS, ws + 5 * N_CELLS };
    float* damping = ws + 6 * N_CELLS;

    init_kernel<<<N_CELLS / 256, 256, 0, stream>>>(vz[0], sxz[0], syz[0], damping);

    for (int t = 0; t < N_STEPS; ++t) {
        const int a = t & 1;
        const int b = a ^ 1;
        step_kernel<<<NX, NY, 0, stream>>>(
            vz[a], sxz[a], syz[a],
            vz[b], sxz[b], syz[b],
            damping, traj, t,
            out + (size_t)t * N_CELLS,
            out + (size_t)(N_STEPS + t) * N_CELLS);
    }
}

// Round 2
// 521.294 us; speedup vs baseline: 1.5345x; 1.5345x over previous
//
#include <hip/hip_runtime.h>
#include <math.h>

#define NX 256
#define NY 256
#define N_STEPS 300
#define N_CELLS (NX * NY)
#define TILE 16
#define HALO 8
#define RDIM 32          // region = TILE + 2*HALO
#define LSTR 33          // LDS row stride (33 floats -> <=2-way bank aliasing, free)
#define LROWS 34         // 32 region rows + 1 pad row each side

// f32 constants (double-precision fold -> f32, matching XLA trace-time folding)
#define kINV_DX       1280.0f
#define kINV_DY       1280.0f
#define kDT           2.5e-5f
#define kMU           25000.0f
#define kETA          0.1f
#define kDT_OVER_RHO  2.5e-8f
#define kONE_MINUS_BD 0.99999975f
#define kNEG_INV_2SIG2 (-55555.5546875f)   // -1/(2*0.003^2)
#define kDX           7.8125e-4f
#define kEPS          1e-8f

// physical LDS index for region cell (rr, cc); rr,cc in [-1, RDIM+1)
#define LIDX(rr, cc) (((rr) + 1) * LSTR + ((cc) + 1))

// PML damping profile value for 1-D global index k (0..255)
__device__ __forceinline__ float dprof(int k) {
    int m = min(k, NX - 1 - k);
    if (m >= 20) return 1.0f;
    float arg = 3.14159265358979f * (float)(20 - m) / 20.0f;
    return 1.0f - 0.05f * (0.5f + 0.5f * cosf(arg));
}

__global__ __launch_bounds__(256) void init_kernel(float* __restrict__ vz,
                                                   float* __restrict__ sxz,
                                                   float* __restrict__ syz) {
    int idx = blockIdx.x * 256 + threadIdx.x;
    vz[idx]  = 0.0f;
    sxz[idx] = 0.0f;
    syz[idx] = 0.0f;
}

template <int K>
__global__ __launch_bounds__(256) void fused_kernel(
    const float* __restrict__ vz_in,
    const float* __restrict__ sxz_in,
    const float* __restrict__ syz_in,
    float* __restrict__ vz_out,
    float* __restrict__ sxz_out,
    float* __restrict__ syz_out,
    const float2* __restrict__ traj,
    int t0,
    float* __restrict__ out)
{
    __shared__ float s_vz[LROWS * LSTR];
    __shared__ float s_sx[LROWS * LSTR];
    __shared__ float s_sy[LROWS * LSTR];

    const int tid = threadIdx.x;
    const int r   = tid >> 3;          // region row, 0..31
    const int m   = tid & 7;
    const int c0  = m << 2;            // region col base, 0,4,...,28

    const int gi  = (int)blockIdx.y * TILE + r  - HALO;   // global row
    const int gj0 = (int)blockIdx.x * TILE + c0 - HALO;   // global col base

    const bool rowOK = (gi >= 0) && (gi < NX);
    const float dpx = rowOK ? dprof(gi) : 0.0f;
    const float xi  = ((float)gi + 0.5f) * kDX;

    bool cellOK[4];
    float damp[4], yj[4];
    #pragma unroll
    for (int k = 0; k < 4; ++k) {
        const int gj = gj0 + k;
        const bool cOK = (gj >= 0) && (gj < NY);
        cellOK[k] = rowOK && cOK;
        damp[k]   = cellOK[k] ? (dpx * dprof(gj)) : 0.0f;
        yj[k]     = ((float)gj + 0.5f) * kDX;
    }

    const bool owned = (r >= HALO) && (r < HALO + TILE) &&
                       (c0 >= HALO) && (c0 + 3 < HALO + TILE);

    // preload trajectory for the fused steps into registers (static index)
    float2 tr[K];
    #pragma unroll
    for (int s = 0; s < K; ++s) tr[s] = traj[t0 + s];

    // load state: vz -> LDS, strain -> registers
    float sxr[4], syr[4];
    #pragma unroll
    for (int k = 0; k < 4; ++k) {
        const int ck = c0 + k;
        float v = 0.0f, sx = 0.0f, sy = 0.0f;
        if (cellOK[k]) {
            const int g = gi * NY + gj0 + k;
            v  = vz_in[g];
            sx = sxz_in[g];
            sy = syz_in[g];
        }
        s_vz[LIDX(r, ck)] = v;
        sxr[k] = sx;
        syr[k] = sy;
    }
    __syncthreads();

    #pragma unroll
    for (int s = 0; s < K; ++s) {
        const float x_t = tr[s].x;
        const float y_t = tr[s].y;

        float vzc[4], sgx[4], sgy[4];
        // ---- phase A: strain update + sigma (writes s_sx, s_sy) ----
        #pragma unroll
        for (int k = 0; k < 4; ++k) {
            const int ck = c0 + k;
            const int gj = gj0 + k;
            const float v = s_vz[LIDX(r, ck)];
            vzc[k] = v;
            const float dvx = (gi < NX - 1) ? (s_vz[LIDX(r + 1, ck)] - v) * kINV_DX : 0.0f;
            const float dvy = (gj < NY - 1) ? (s_vz[LIDX(r, ck + 1)] - v) * kINV_DY : 0.0f;
            sxr[k] += dvx * kDT;
            syr[k] += dvy * kDT;
            const float gx = kMU * sxr[k] + kETA * dvx;
            const float gy = kMU * syr[k] + kETA * dvy;
            s_sx[LIDX(r, ck)] = gx;
            s_sy[LIDX(r, ck)] = gy;
            sgx[k] = gx;
            sgy[k] = gy;
        }
        if (owned) {
            float4 sm;
            sm.x = sqrtf(sgx[0] * sgx[0] + sgy[0] * sgy[0] + kEPS);
            sm.y = sqrtf(sgx[1] * sgx[1] + sgy[1] * sgy[1] + kEPS);
            sm.z = sqrtf(sgx[2] * sgx[2] + sgy[2] * sgy[2] + kEPS);
            sm.w = sqrtf(sgx[3] * sgx[3] + sgy[3] * sgy[3] + kEPS);
            *(float4*)&out[(size_t)(N_STEPS + t0 + s) * N_CELLS + gi * NY + gj0] = sm;
        }
        __syncthreads();

        // ---- phase B: stress divergence + source + velocity update ----
        float4 vout;
        #pragma unroll
        for (int k = 0; k < 4; ++k) {
            const int ck = c0 + k;
            const int gj = gj0 + k;
            const float dsx = (gi > 0) ? (sgx[k] - s_sx[LIDX(r - 1, ck)]) * kINV_DX : 0.0f;
            const float sy_m = (k == 0) ? s_sy[LIDX(r, ck - 1)] : sgy[k - 1];
            const float dsy = (gj > 0) ? (sgy[k] - sy_m) * kINV_DY : 0.0f;
            const float rx = xi - x_t;
            const float ry = yj[k] - y_t;
            const float src = expf((rx * rx + ry * ry) * kNEG_INV_2SIG2);
            const float vn = (vzc[k] + kDT_OVER_RHO * (dsx + dsy + src)) *
                             kONE_MINUS_BD * damp[k];
            s_vz[LIDX(r, ck)] = vn;   // own-cell in-place write (no cross-reads in phase B)
            ((float*)&vout)[k] = vn;
        }
        if (owned) {
            *(float4*)&out[(size_t)(t0 + s) * N_CELLS + gi * NY + gj0] = vout;
        }
        __syncthreads();
    }

    // store owned state for next launch
    if (owned) {
        const int g = gi * NY + gj0;
        float4 vz4;
        vz4.x = s_vz[LIDX(r, c0 + 0)];
        vz4.y = s_vz[LIDX(r, c0 + 1)];
        vz4.z = s_vz[LIDX(r, c0 + 2)];
        vz4.w = s_vz[LIDX(r, c0 + 3)];
        *(float4*)&vz_out[g]  = vz4;
        *(float4*)&sxz_out[g] = make_float4(sxr[0], sxr[1], sxr[2], sxr[3]);
        *(float4*)&syz_out[g] = make_float4(syr[0], syr[1], syr[2], syr[3]);
    }
}

extern "C" void kernel_launch(void* const* d_in, const int* in_sizes, int n_in,
                              void* d_out, int out_size, void* d_ws, size_t ws_size,
                              hipStream_t stream) {
    const float2* traj = (const float2*)d_in[0];
    float* out = (float*)d_out;
    float* ws  = (float*)d_ws;

    // workspace: vz[2], sxz[2], syz[2]  -> 6 * 64K floats = 1.5 MB
    float* vz[2]  = { ws + 0 * N_CELLS, ws + 1 * N_CELLS };
    float* sxz[2] = { ws + 2 * N_CELLS, ws + 3 * N_CELLS };
    float* syz[2] = { ws + 4 * N_CELLS, ws + 5 * N_CELLS };

    init_kernel<<<N_CELLS / 256, 256, 0, stream>>>(vz[0], sxz[0], syz[0]);

    const dim3 grid(NX / TILE, NY / TILE);
    int t0 = 0, l = 0;
    for (; t0 + 8 <= N_STEPS; t0 += 8, ++l) {
        const int a = l & 1, b = a ^ 1;
        fused_kernel<8><<<grid, 256, 0, stream>>>(
            vz[a], sxz[a], syz[a], vz[b], sxz[b], syz[b], traj, t0, out);
    }
    if (t0 < N_STEPS) {
        const int a = l & 1, b = a ^ 1;
        fused_kernel<4><<<grid, 256, 0, stream>>>(
            vz[a], sxz[a], syz[a], vz[b], sxz[b], syz[b], traj, t0, out);
    }
}

// Round 3
// 280.208 us; speedup vs baseline: 2.8548x; 1.8604x over previous
//
#include <hip/hip_runtime.h>
#include <math.h>

#define NX 256
#define NY 256
#define N_STEPS 300
#define N_CELLS (NX * NY)
#define TILE 16
#define HALO 8
#define LSTR 36              // LDS row stride in floats (bank phase 4/row, float2-aligned)
#define LROWS 34             // rows -1..32
#define LIDX(rr, cc) (((rr) + 1) * LSTR + ((cc) + 2))

// f32 constants (double-precision fold -> f32, matching XLA trace-time folding)
#define kINV_DX       1280.0f
#define kINV_DY       1280.0f
#define kDT           2.5e-5f
#define kMU           25000.0f
#define kETA          0.1f
#define kDT_OVER_RHO  2.5e-8f
#define kONE_MINUS_BD 0.99999975f
#define kNEG_INV_2SIG2 (-55555.5546875f)   // -1/(2*0.003^2)
#define kDX           7.8125e-4f
#define kEPS          1e-8f

// PML damping profile value for 1-D global index k (0..255)
__device__ __forceinline__ float dprof(int k) {
    int m = min(k, NX - 1 - k);
    if (m >= 20) return 1.0f;
    float arg = 3.14159265358979f * (float)(20 - m) / 20.0f;
    return 1.0f - 0.05f * (0.5f + 0.5f * cosf(arg));
}

template <int K, bool FIRST, bool LAST>
__global__ __launch_bounds__(512) void fused_kernel(
    const float* __restrict__ vz_in,
    const float* __restrict__ sxz_in,
    const float* __restrict__ syz_in,
    float* __restrict__ vz_out,
    float* __restrict__ sxz_out,
    float* __restrict__ syz_out,
    const float2* __restrict__ traj,
    int t0,
    float* __restrict__ out)
{
    __shared__ float s_vz[2][LROWS * LSTR];

    const int tid = threadIdx.x;
    const int r   = tid >> 4;            // region row, 0..31
    const int c0  = (tid & 15) << 1;     // region col base, 0,2,...,30

    const int gi  = (int)blockIdx.y * TILE + r  - HALO;
    const int gj0 = (int)blockIdx.x * TILE + c0 - HALO;
    const int g   = gi * NY + gj0;

    const bool rowOK  = (gi >= 0) && (gi < NX);
    const bool colOK  = (gj0 >= 0) && (gj0 < NY);   // pair never straddles (even)
    const bool inD    = rowOK && colOK;
    const bool fwdX   = (gi < NX - 1);
    const bool fwdY1  = (gj0 + 1 < NY - 1);
    const bool backX  = (gi > 0);
    const bool backY0 = (gj0 > 0);

    const float dpx   = rowOK ? dprof(gi) : 0.0f;
    const float damp0 = inD ? dpx * dprof(gj0) : 0.0f;
    const float damp1 = inD ? dpx * dprof(gj0 + 1) : 0.0f;
    const float xi    = ((float)gi + 0.5f) * kDX;
    const float yj0   = ((float)gj0 + 0.5f) * kDX;
    const float yj1   = ((float)gj0 + 1.5f) * kDX;

    const bool owned = (r >= HALO) && (r < HALO + TILE) &&
                       (c0 >= HALO) && (c0 + 1 < HALO + TILE);

    // trajectory for fused steps (uniform -> scalar regs)
    float trx[K], tryy[K];
    #pragma unroll
    for (int s = 0; s < K; ++s) { float2 t2 = traj[t0 + s]; trx[s] = t2.x; tryy[s] = t2.y; }

    // zero LDS (both buffers incl. pads)
    for (int idx = tid; idx < 2 * LROWS * LSTR; idx += 512)
        ((float*)s_vz)[idx] = 0.0f;

    // load state
    float vz0 = 0.f, vz1 = 0.f, sx0 = 0.f, sx1 = 0.f, sy0 = 0.f, sy1 = 0.f;
    float sxm0 = 0.f, sxm1 = 0.f, symv = 0.f;
    if (!FIRST) {
        if (inD) {
            float2 v2 = *(const float2*)&vz_in[g];  vz0 = v2.x; vz1 = v2.y;
            float2 a2 = *(const float2*)&sxz_in[g]; sx0 = a2.x; sx1 = a2.y;
            float2 b2 = *(const float2*)&syz_in[g]; sy0 = b2.x; sy1 = b2.y;
        }
        if ((gi - 1 >= 0) && (gi - 1 < NX) && colOK) {
            float2 m2 = *(const float2*)&sxz_in[g - NY]; sxm0 = m2.x; sxm1 = m2.y;
        }
        if (rowOK && (gj0 - 1 >= 0)) symv = syz_in[g - 1];
    }
    __syncthreads();
    *(float2*)&s_vz[0][LIDX(r, c0)] = make_float2(vz0, vz1);
    __syncthreads();

    #pragma unroll
    for (int s = 0; s < K; ++s) {
        const int cur = s & 1, nxt = cur ^ 1;
        const float x_t = trx[s], y_t = tryy[s];

        const float2 vp = *(const float2*)&s_vz[cur][LIDX(r + 1, c0)];
        const float2 vm = *(const float2*)&s_vz[cur][LIDX(r - 1, c0)];
        const float vr2 = s_vz[cur][LIDX(r, c0 + 2)];
        const float vl1 = s_vz[cur][LIDX(r, c0 - 1)];

        // forward differences at own cells
        const float dvx0 = fwdX  ? (vp.x - vz0) * kINV_DX : 0.0f;
        const float dvx1 = fwdX  ? (vp.y - vz1) * kINV_DX : 0.0f;
        const float dvy0 = (vz1 - vz0) * kINV_DY;                 // gj0 <= 254 always when valid
        const float dvy1 = fwdY1 ? (vr2 - vz1) * kINV_DY : 0.0f;

        // own strain/sigma
        sx0 += dvx0 * kDT; sx1 += dvx1 * kDT;
        sy0 += dvy0 * kDT; sy1 += dvy1 * kDT;
        const float gx0 = kMU * sx0 + kETA * dvx0;
        const float gx1 = kMU * sx1 + kETA * dvx1;
        const float gy0 = kMU * sy0 + kETA * dvy0;
        const float gy1 = kMU * sy1 + kETA * dvy1;

        // halo strain/sigma (row above, col left) maintained redundantly
        const float dxm0 = (vz0 - vm.x) * kINV_DX;
        const float dxm1 = (vz1 - vm.y) * kINV_DX;
        sxm0 += dxm0 * kDT; sxm1 += dxm1 * kDT;
        const float gxm0 = kMU * sxm0 + kETA * dxm0;
        const float gxm1 = kMU * sxm1 + kETA * dxm1;
        const float dym = (vz0 - vl1) * kINV_DY;
        symv += dym * kDT;
        const float gym = kMU * symv + kETA * dym;

        // stress divergence
        const float dsx0 = backX  ? (gx0 - gxm0) * kINV_DX : 0.0f;
        const float dsx1 = backX  ? (gx1 - gxm1) * kINV_DX : 0.0f;
        const float dsy0 = backY0 ? (gy0 - gym) * kINV_DY : 0.0f;
        const float dsy1 = (gy1 - gy0) * kINV_DY;                 // gj0+1 >= 1 when valid

        // Gaussian source
        const float rx  = xi - x_t;
        const float ry0 = yj0 - y_t;
        const float ry1 = yj1 - y_t;
        const float src0 = expf((rx * rx + ry0 * ry0) * kNEG_INV_2SIG2);
        const float src1 = expf((rx * rx + ry1 * ry1) * kNEG_INV_2SIG2);

        // velocity update
        vz0 = (vz0 + kDT_OVER_RHO * (dsx0 + dsy0 + src0)) * kONE_MINUS_BD * damp0;
        vz1 = (vz1 + kDT_OVER_RHO * (dsx1 + dsy1 + src1)) * kONE_MINUS_BD * damp1;

        *(float2*)&s_vz[nxt][LIDX(r, c0)] = make_float2(vz0, vz1);

        if (owned) {
            *(float2*)&out[(size_t)(t0 + s) * N_CELLS + g] = make_float2(vz0, vz1);
            const float sm0 = sqrtf(gx0 * gx0 + gy0 * gy0 + kEPS);
            const float sm1 = sqrtf(gx1 * gx1 + gy1 * gy1 + kEPS);
            *(float2*)&out[(size_t)(N_STEPS + t0 + s) * N_CELLS + g] = make_float2(sm0, sm1);
        }
        __syncthreads();
    }

    if (!LAST && owned) {
        *(float2*)&vz_out[g]  = make_float2(vz0, vz1);
        *(float2*)&sxz_out[g] = make_float2(sx0, sx1);
        *(float2*)&syz_out[g] = make_float2(sy0, sy1);
    }
}

extern "C" void kernel_launch(void* const* d_in, const int* in_sizes, int n_in,
                              void* d_out, int out_size, void* d_ws, size_t ws_size,
                              hipStream_t stream) {
    const float2* traj = (const float2*)d_in[0];
    float* out = (float*)d_out;
    float* ws  = (float*)d_ws;

    float* vz[2]  = { ws + 0 * N_CELLS, ws + 1 * N_CELLS };
    float* sxz[2] = { ws + 2 * N_CELLS, ws + 3 * N_CELLS };
    float* syz[2] = { ws + 4 * N_CELLS, ws + 5 * N_CELLS };

    const dim3 grid(NX / TILE, NY / TILE);

    // launch l reads set (l&1), writes set ((l&1)^1); l=0 ignores input (FIRST)
    int l = 0, t0 = 0;
    fused_kernel<8, true, false><<<grid, 512, 0, stream>>>(
        vz[0], sxz[0], syz[0], vz[1], sxz[1], syz[1], traj, 0, out);
    ++l; t0 += 8;
    for (; t0 + 8 <= N_STEPS - 4; t0 += 8, ++l) {
        const int a = l & 1, b = a ^ 1;
        fused_kernel<8, false, false><<<grid, 512, 0, stream>>>(
            vz[a], sxz[a], syz[a], vz[b], sxz[b], syz[b], traj, t0, out);
    }
    {   // tail: 4 steps, no state store needed
        const int a = l & 1, b = a ^ 1;
        fused_kernel<4, false, true><<<grid, 512, 0, stream>>>(
            vz[a], sxz[a], syz[a], vz[b], sxz[b], syz[b], traj, t0, out);
    }
}